// Round 3
// baseline (112.955 us; speedup 1.0000x reference)
//
#include <hip/hip_runtime.h>

// Problem constants (match reference)
#define BB 8
#define NN 512
#define NUM_GT 64
#define CC 16
#define FHH 16
#define FWW 16

// Output layout (floats):
//   label_map: [B*N][C][FH][FW]  -> 4096*4096 = 16777216
//   offset:    [B*N][4][FH][FW]  -> 4096*1024 =  4194304
//   mask:      [B*N][C]          -> 4096*16   =    65536
#define LM_FLOATS (BB*NN*CC*FHH*FWW)      // 16777216
#define OFF_FLOATS (BB*NN*4*FHH*FWW)      // 4194304

// Native clang vector type: __builtin_nontemporal_store requires a pointer
// to scalar-or-vector-of-scalar, not HIP's float4 class type.
typedef float fx4 __attribute__((ext_vector_type(4)));

// MEASUREMENT ROUND: identical verified kernel, launched TWICE.
// Delta vs round-2 dur_us (99.7) = kernel self time K.
//   K ~ 15us  -> kernel already at write roofline (harness fill+reset dominates)
//   K ~ 42us  -> ~28us still on the table in the store path
__global__ __launch_bounds__(256) void rcnn_encode_kernel(
    const float* __restrict__ boxes,          // (B,N,4)
    const float* __restrict__ gt_boxes,       // (B,NUM_GT,5)
    const int*   __restrict__ match_pos_flag, // (B,N)
    const int*   __restrict__ match_gt_id,    // (B,N)
    float* __restrict__ out)
{
    const int bn  = blockIdx.x;          // 0..B*N-1
    const int b   = bn >> 9;             // bn / N  (N=512)
    const int tid = threadIdx.x;         // 0..255

    // ---- per-(b,n) scalars (computed redundantly; loads broadcast) ----
    const float bx1 = boxes[bn*4+0];
    const float by1 = boxes[bn*4+1];
    const float bx2 = boxes[bn*4+2];
    const float by2 = boxes[bn*4+3];

    const int gid  = match_gt_id[bn];
    const int gidc = min(max(gid, 0), NUM_GT-1);       // clamp like reference
    const float* g = gt_boxes + (size_t)(b*NUM_GT + gidc)*5;
    const float gx1 = g[0], gy1 = g[1], gx2 = g[2], gy2 = g[3], label = g[4];
    const int flag = match_pos_flag[bn];

    // zoom boxes by (1.1, 1.1)
    const float cx = (bx1 + bx2) * 0.5f;
    const float cy = (by1 + by2) * 0.5f;
    const float zw = (bx2 - bx1) * 1.1f;
    const float zh = (by2 - by1) * 1.1f;
    const float ax1 = cx - zw * 0.5f;
    const float ay1 = cy - zh * 0.5f;
    const float ax2 = cx + zw * 0.5f;
    const float ay2 = cy + zh * 0.5f;

    const float rx1 = gx1 - ax1;
    const float ry1 = gy1 - ay1;
    const float rx2 = gx2 - ax1;
    const float ry2 = gy2 - ay1;
    const float rw  = rx2 - rx1;
    const float rh  = ry2 - ry1;
    const float rcx = (rx1 + rx2) * 0.5f;
    const float rcy = (ry1 + ry2) * 0.5f;
    const float sw  = (ax2 - ax1) / 16.0f;   // /FW, exact pow2 scale
    const float sh  = (ay2 - ay1) / 16.0f;

    const float w_sigma = (rw * 0.5f) / sw;  // rw/2/sw
    const float h_sigma = (rh * 0.5f) / sh;
    const float w_sig_s = fmaxf(w_sigma, 1.5f);
    const float h_sig_s = fmaxf(h_sigma, 1.5f);
    const float w_sig_c = fmaxf(w_sigma, 0.5f);
    const float h_sig_c = fmaxf(h_sigma, 0.5f);
    const float pos_w = rcx / sw;
    const float pos_h = rcy / sh;
    const bool  small = (sw < 0.01f) || (sh < 0.01f);

    // offset plane values (per-axis)
    const float ox1v = rx1 / sw;
    const float oy1v = ry1 / sh;
    const float ox2v = rx2 / sw;
    const float oy2v = ry2 / sh;

    const float c_match = fabsf(label) - 1.0f;   // float compare like reference

    // Geometry of this thread's float4s (position p = (tid&63)*4 + j):
    //   row  fh = (tid&63)>>2   (constant across j and k)
    //   cols fw = (tid&3)*4 + j
    const float fh_f = (float)((tid & 63) >> 2);
    const float fw0  = (float)((tid & 3) << 2);

    // ---- label_map: 4096 floats per bn = 1024 float4; 4 per thread ----
    {
        fx4* lm = (fx4*)out + (size_t)bn * 1024;
        // h-terms are per-thread constants
        const float ht   = ((pos_h - fh_f) - 0.5f) / h_sig_s;
        const float ht2  = ht * ht;
        const bool cond_h = fabsf((fh_f + 0.5f) - pos_h) < h_sig_c;
        #pragma unroll
        for (int k = 0; k < 4; ++k) {
            const int f = k*256 + tid;           // float4 idx in [0,1024)
            const int c = f >> 6;                // channel (wave-uniform)
            fx4 v = (fx4)(0.0f);
            if (((float)c == c_match) && !small) {   // wave-uniform branch
                #pragma unroll
                for (int j = 0; j < 4; ++j) {
                    const float fw_ = fw0 + (float)j;
                    const float wt  = ((pos_w - fw_) - 0.5f) / w_sig_s;
                    const bool cond = cond_h &&
                                      (fabsf((fw_ + 0.5f) - pos_w) < w_sig_c);
                    v[j] = cond ? expf(-(wt*wt + ht2)) : 0.0f;
                }
            }
            __builtin_nontemporal_store(v, lm + f);
        }
    }

    // ---- offset: 1024 floats per bn = 256 float4; 1 per thread ----
    {
        fx4* of = (fx4*)(out + (size_t)LM_FLOATS) + (size_t)bn * 256;
        const int comp = tid >> 6;               // 0..3 (wave-uniform)
        fx4 v;
        if (small) {
            v = (fx4)(0.0f);
        } else if (comp == 0) {
            #pragma unroll
            for (int j = 0; j < 4; ++j)
                v[j] = ox1v - ((fw0 + (float)j) + 0.5f);
        } else if (comp == 1) {
            v = (fx4)(oy1v - (fh_f + 0.5f));
        } else if (comp == 2) {
            #pragma unroll
            for (int j = 0; j < 4; ++j)
                v[j] = ox2v - ((fw0 + (float)j) + 0.5f);
        } else {
            v = (fx4)(oy2v - (fh_f + 0.5f));
        }
        __builtin_nontemporal_store(v, of + tid);
    }

    // ---- mask: 16 floats per bn (no `small` filter, matches reference) ----
    if (tid < CC) {
        const bool pos_match = flag > 0;
        const float nnl = (flag != 0) ? label : 0.0f;   // non_neg_label
        const bool mask_one = pos_match && (nnl > 0.0f); // CLS_ON_HARD=False
        const bool m = ((float)tid == c_match) && mask_one;
        __builtin_nontemporal_store(m ? 1.0f : 0.0f,
            out + (size_t)LM_FLOATS + (size_t)OFF_FLOATS + (size_t)bn*CC + tid);
    }
}

extern "C" void kernel_launch(void* const* d_in, const int* in_sizes, int n_in,
                              void* d_out, int out_size, void* d_ws, size_t ws_size,
                              hipStream_t stream) {
    const float* boxes          = (const float*)d_in[0];
    const float* gt_boxes       = (const float*)d_in[1];
    const int*   match_pos_flag = (const int*)d_in[2];
    const int*   match_gt_id    = (const int*)d_in[3];
    float* out = (float*)d_out;

    // Launch TWICE (idempotent, deterministic writes -> same output).
    // dur_us delta vs single-launch == kernel self time.
    rcnn_encode_kernel<<<BB*NN, 256, 0, stream>>>(
        boxes, gt_boxes, match_pos_flag, match_gt_id, out);
    rcnn_encode_kernel<<<BB*NN, 256, 0, stream>>>(
        boxes, gt_boxes, match_pos_flag, match_gt_id, out);
}

// Round 4
// 99.199 us; speedup vs baseline: 1.1387x; 1.1387x over previous
//
#include <hip/hip_runtime.h>

// Problem constants (match reference)
#define BB 8
#define NN 512
#define NUM_GT 64
#define CC 16
#define FHH 16
#define FWW 16

// Output layout (floats):
//   label_map: [B*N][C][FH][FW]  -> 4096*4096 = 16777216
//   offset:    [B*N][4][FH][FW]  -> 4096*1024 =  4194304
//   mask:      [B*N][C]          -> 4096*16   =    65536
#define LM_FLOATS (BB*NN*CC*FHH*FWW)      // 16777216
#define OFF_FLOATS (BB*NN*4*FHH*FWW)      // 4194304

// Native clang vector type: __builtin_nontemporal_store requires a pointer
// to scalar-or-vector-of-scalar, not HIP's float4 class type.
typedef float fx4 __attribute__((ext_vector_type(4)));

// ROOFLINE-BOUND: kernel self-time measured at ~13.3us via double-launch
// A/B (round 3: 99.7 -> 113.0 us with 2x launch). 84.1 MB of output at
// 6.3 TB/s achievable write BW = 13.4us floor -> kernel is AT the write
// roofline. Remaining dur_us is harness re-poison fill (~55us, itself
// BW-bound) + reset dispatches. Barrier-free, pure NT-store stream.
__global__ __launch_bounds__(256) void rcnn_encode_kernel(
    const float* __restrict__ boxes,          // (B,N,4)
    const float* __restrict__ gt_boxes,       // (B,NUM_GT,5)
    const int*   __restrict__ match_pos_flag, // (B,N)
    const int*   __restrict__ match_gt_id,    // (B,N)
    float* __restrict__ out)
{
    const int bn  = blockIdx.x;          // 0..B*N-1
    const int b   = bn >> 9;             // bn / N  (N=512)
    const int tid = threadIdx.x;         // 0..255

    // ---- per-(b,n) scalars (computed redundantly; loads broadcast) ----
    const float bx1 = boxes[bn*4+0];
    const float by1 = boxes[bn*4+1];
    const float bx2 = boxes[bn*4+2];
    const float by2 = boxes[bn*4+3];

    const int gid  = match_gt_id[bn];
    const int gidc = min(max(gid, 0), NUM_GT-1);       // clamp like reference
    const float* g = gt_boxes + (size_t)(b*NUM_GT + gidc)*5;
    const float gx1 = g[0], gy1 = g[1], gx2 = g[2], gy2 = g[3], label = g[4];
    const int flag = match_pos_flag[bn];

    // zoom boxes by (1.1, 1.1)
    const float cx = (bx1 + bx2) * 0.5f;
    const float cy = (by1 + by2) * 0.5f;
    const float zw = (bx2 - bx1) * 1.1f;
    const float zh = (by2 - by1) * 1.1f;
    const float ax1 = cx - zw * 0.5f;
    const float ay1 = cy - zh * 0.5f;
    const float ax2 = cx + zw * 0.5f;
    const float ay2 = cy + zh * 0.5f;

    const float rx1 = gx1 - ax1;
    const float ry1 = gy1 - ay1;
    const float rx2 = gx2 - ax1;
    const float ry2 = gy2 - ay1;
    const float rw  = rx2 - rx1;
    const float rh  = ry2 - ry1;
    const float rcx = (rx1 + rx2) * 0.5f;
    const float rcy = (ry1 + ry2) * 0.5f;
    const float sw  = (ax2 - ax1) / 16.0f;   // /FW, exact pow2 scale
    const float sh  = (ay2 - ay1) / 16.0f;

    const float w_sigma = (rw * 0.5f) / sw;  // rw/2/sw
    const float h_sigma = (rh * 0.5f) / sh;
    const float w_sig_s = fmaxf(w_sigma, 1.5f);
    const float h_sig_s = fmaxf(h_sigma, 1.5f);
    const float w_sig_c = fmaxf(w_sigma, 0.5f);
    const float h_sig_c = fmaxf(h_sigma, 0.5f);
    const float pos_w = rcx / sw;
    const float pos_h = rcy / sh;
    const bool  small = (sw < 0.01f) || (sh < 0.01f);

    // offset plane values (per-axis)
    const float ox1v = rx1 / sw;
    const float oy1v = ry1 / sh;
    const float ox2v = rx2 / sw;
    const float oy2v = ry2 / sh;

    const float c_match = fabsf(label) - 1.0f;   // float compare like reference

    // Geometry of this thread's float4s (position p = (tid&63)*4 + j):
    //   row  fh = (tid&63)>>2   (constant across j and k)
    //   cols fw = (tid&3)*4 + j
    const float fh_f = (float)((tid & 63) >> 2);
    const float fw0  = (float)((tid & 3) << 2);

    // ---- label_map: 4096 floats per bn = 1024 float4; 4 per thread ----
    {
        fx4* lm = (fx4*)out + (size_t)bn * 1024;
        // h-terms are per-thread constants
        const float ht   = ((pos_h - fh_f) - 0.5f) / h_sig_s;
        const float ht2  = ht * ht;
        const bool cond_h = fabsf((fh_f + 0.5f) - pos_h) < h_sig_c;
        #pragma unroll
        for (int k = 0; k < 4; ++k) {
            const int f = k*256 + tid;           // float4 idx in [0,1024)
            const int c = f >> 6;                // channel (wave-uniform)
            fx4 v = (fx4)(0.0f);
            if (((float)c == c_match) && !small) {   // wave-uniform branch
                #pragma unroll
                for (int j = 0; j < 4; ++j) {
                    const float fw_ = fw0 + (float)j;
                    const float wt  = ((pos_w - fw_) - 0.5f) / w_sig_s;
                    const bool cond = cond_h &&
                                      (fabsf((fw_ + 0.5f) - pos_w) < w_sig_c);
                    v[j] = cond ? expf(-(wt*wt + ht2)) : 0.0f;
                }
            }
            __builtin_nontemporal_store(v, lm + f);
        }
    }

    // ---- offset: 1024 floats per bn = 256 float4; 1 per thread ----
    {
        fx4* of = (fx4*)(out + (size_t)LM_FLOATS) + (size_t)bn * 256;
        const int comp = tid >> 6;               // 0..3 (wave-uniform)
        fx4 v;
        if (small) {
            v = (fx4)(0.0f);
        } else if (comp == 0) {
            #pragma unroll
            for (int j = 0; j < 4; ++j)
                v[j] = ox1v - ((fw0 + (float)j) + 0.5f);
        } else if (comp == 1) {
            v = (fx4)(oy1v - (fh_f + 0.5f));
        } else if (comp == 2) {
            #pragma unroll
            for (int j = 0; j < 4; ++j)
                v[j] = ox2v - ((fw0 + (float)j) + 0.5f);
        } else {
            v = (fx4)(oy2v - (fh_f + 0.5f));
        }
        __builtin_nontemporal_store(v, of + tid);
    }

    // ---- mask: 16 floats per bn (no `small` filter, matches reference) ----
    if (tid < CC) {
        const bool pos_match = flag > 0;
        const float nnl = (flag != 0) ? label : 0.0f;   // non_neg_label
        const bool mask_one = pos_match && (nnl > 0.0f); // CLS_ON_HARD=False
        const bool m = ((float)tid == c_match) && mask_one;
        __builtin_nontemporal_store(m ? 1.0f : 0.0f,
            out + (size_t)LM_FLOATS + (size_t)OFF_FLOATS + (size_t)bn*CC + tid);
    }
}

extern "C" void kernel_launch(void* const* d_in, const int* in_sizes, int n_in,
                              void* d_out, int out_size, void* d_ws, size_t ws_size,
                              hipStream_t stream) {
    const float* boxes          = (const float*)d_in[0];
    const float* gt_boxes       = (const float*)d_in[1];
    const int*   match_pos_flag = (const int*)d_in[2];
    const int*   match_gt_id    = (const int*)d_in[3];
    float* out = (float*)d_out;

    rcnn_encode_kernel<<<BB*NN, 256, 0, stream>>>(
        boxes, gt_boxes, match_pos_flag, match_gt_id, out);
}